// Round 3
// baseline (118.666 us; speedup 1.0000x reference)
//
#include <hip/hip_runtime.h>
#include <hip/hip_bf16.h>
#include <cstdint>

#define B_TOK 4096
#define DDIM  2048
#define KR    512
#define NE    8

using f32x4  = __attribute__((ext_vector_type(4))) float;
using short8 = __attribute__((ext_vector_type(8))) short;
using u16 = unsigned short;

__device__ inline u16 f2bf(float f) {
    union { float f; uint32_t u; } x; x.f = f;
    uint32_t u = x.u;
    return (u16)((u + 0x7fffu + ((u >> 16) & 1u)) >> 16);  // RNE
}

__device__ inline void gload_lds16(const u16* g, u16* l) {
    __builtin_amdgcn_global_load_lds(
        (const __attribute__((address_space(1))) void*)g,
        (__attribute__((address_space(3))) void*)l, 16, 0, 0);
}

// ---------------- conversion: f32 2D block -> bf16 2D block ----------------
__global__ void cvt_copy2d(const float* __restrict__ src, u16* __restrict__ dst,
                           int rows, int cols4, int src_ld, int dst_ld) {
    int total = rows * cols4;
    for (int i = blockIdx.x * blockDim.x + threadIdx.x; i < total;
         i += gridDim.x * blockDim.x) {
        int r = i / cols4, c = i - r * cols4;
        float4 val = *((const float4*)(src + (size_t)r * src_ld) + c);
        ushort4 o;
        o.x = f2bf(val.x); o.y = f2bf(val.y); o.z = f2bf(val.z); o.w = f2bf(val.w);
        *((ushort4*)(dst + (size_t)r * dst_ld) + c) = o;
    }
}

// ---------------- transpose U (D,K) f32 -> U^T (K,D) bf16 ----------------
__global__ void transpose_cvt(const float* __restrict__ src, u16* __restrict__ dst,
                              int src_cols /*K*/, int dst_ld /*D*/) {
    __shared__ float tile[32][33];
    int c0 = blockIdx.x * 32;
    int r0 = blockIdx.y * 32;
    int tx = threadIdx.x, ty = threadIdx.y; // 32 x 8
    #pragma unroll
    for (int j = 0; j < 32; j += 8)
        tile[ty + j][tx] = src[(size_t)(r0 + ty + j) * src_cols + c0 + tx];
    __syncthreads();
    #pragma unroll
    for (int j = 0; j < 32; j += 8)
        dst[(size_t)(c0 + ty + j) * dst_ld + r0 + tx] = f2bf(tile[tx][ty + j]);
}

// ---------------- router ----------------
__global__ __launch_bounds__(256)
void router_kernel(const float* __restrict__ rt, const float* __restrict__ W1,
                   const float* __restrict__ W2, const float* __restrict__ lam,
                   u16* __restrict__ Aaug) {
    int b = blockIdx.x;
    int tid = threadIdx.x;
    const float* r = rt + (size_t)b * 1024;

    float p = r[tid] * W1[tid] + r[tid + 256] * W1[tid + 256];
    #pragma unroll
    for (int o = 32; o > 0; o >>= 1) p += __shfl_down(p, o);
    __shared__ float sp[4];
    __shared__ float sbc;
    if ((tid & 63) == 0) sp[tid >> 6] = p;
    __syncthreads();
    if (tid == 0) sbc = sp[0] + sp[1] + sp[2] + sp[3];
    __syncthreads();
    float s = sbc;

    float g[NE]; float mx = -1e30f;
    #pragma unroll
    for (int e = 0; e < NE; e++) { g[e] = s * W2[e]; mx = fmaxf(mx, g[e]); }
    float den = 0.f;
    #pragma unroll
    for (int e = 0; e < NE; e++) { g[e] = expf(g[e] - mx); den += g[e]; }
    float inv = 1.0f / den;

    for (int kk = tid; kk < KR; kk += 256) {
        float mu = 0.f;
        #pragma unroll
        for (int e = 0; e < NE; e++) mu += g[e] * lam[e * KR + kk];
        float m = mu * inv * r[512 + kk];
        Aaug[(size_t)b * 2560 + 2048 + kk] = f2bf(m);
    }
}

// ---- bf16 B^T GEMM: 128x128 tile, BK=32, 4-slot LDS ring, prefetch depth 3,
// ---- counted vmcnt gates (T4), raw s_barrier, setprio around MFMA (T5),
// ---- XOR bank swizzle on both sides (T2, rule 21).
// LDS slot (16KB): A 128 rows x 32 u16 at +0, B 128 rows x 32 u16 at +4096.
// Row = 64B = 4 chunks of 16B; chunk swizzle sw(r) = (r>>1)&3.
template<bool HAS_V>
__global__ __launch_bounds__(256, 2)
void gemm_r4(const u16* __restrict__ A, const u16* __restrict__ Bm,
             float* __restrict__ C, const float* __restrict__ v,
             int N, int Kc, int lda, int ldb, int nbx) {
    __shared__ u16 lds[4 * 8192];   // 64 KB

    const int tid = threadIdx.x;
    const int wid = tid >> 6, lane = tid & 63;
    const int l15 = lane & 15, l4 = lane >> 4;
    const int wm = wid >> 1, wn = wid & 1;       // 2x2 waves, 64x64 out each

    const int nwg = gridDim.x;
    const int id = (blockIdx.x & 7) * (nwg >> 3) + (blockIdx.x >> 3);
    const int row0 = (id / nbx) * 128;
    const int col0 = (id % nbx) * 128;

    // staging: thread t covers (row = i*64 + t/4, chunk = t&3) of a 64-row line;
    // source chunk pre-swizzled by sw(row) = (row>>1)&3 = (t>>3)&3.
    const int srow = tid >> 2;
    const int scol = ((tid & 3) ^ ((tid >> 3) & 3)) << 3;
    const u16* gA = A + (size_t)(row0 + srow) * lda + scol;
    const u16* gB = Bm + (size_t)(col0 + srow) * ldb + scol;
    // LDS write cursor for this thread's 16B piece within a 64-row line
    const int lofs = wid * 512;   // + lane*8 implicit in gload_lds

    const int nt = Kc >> 5;       // K-tiles of 32

    f32x4 acc[4][4] = {};

    // prologue: stage tiles 0,1,2 into slots 0,1,2 (nt >= 3 always here)
    #pragma unroll
    for (int p = 0; p < 3; p++) {
        const u16* gAt = gA + p * 32;
        const u16* gBt = gB + p * 32;
        u16* sl = lds + p * 8192;
        gload_lds16(gAt,                     sl + lofs);
        gload_lds16(gAt + (size_t)64 * lda,  sl + 2048 + lofs);
        gload_lds16(gBt,                     sl + 4096 + lofs);
        gload_lds16(gBt + (size_t)64 * ldb,  sl + 6144 + lofs);
    }
    asm volatile("s_waitcnt vmcnt(8)" ::: "memory");   // tile 0 landed
    __builtin_amdgcn_s_barrier();
    __builtin_amdgcn_sched_barrier(0);

    for (int t = 0; t < nt; ++t) {
        // issue tile t+3 into slot (t+3)&3 (that slot was consumed at iter t-1)
        if (t + 3 < nt) {
            const u16* gAt = gA + (t + 3) * 32;
            const u16* gBt = gB + (t + 3) * 32;
            u16* sl = lds + ((t + 3) & 3) * 8192;
            gload_lds16(gAt,                     sl + lofs);
            gload_lds16(gAt + (size_t)64 * lda,  sl + 2048 + lofs);
            gload_lds16(gBt,                     sl + 4096 + lofs);
            gload_lds16(gBt + (size_t)64 * ldb,  sl + 6144 + lofs);
        }

        const u16* a0 = lds + (t & 3) * 8192;
        const u16* b0 = a0 + 4096;
        short8 af[4], bv[4];
        #pragma unroll
        for (int mf = 0; mf < 4; mf++) {
            int row = wm * 64 + mf * 16 + l15;
            int ch = l4 ^ ((row >> 1) & 3);
            af[mf] = *(const short8*)(a0 + row * 32 + ch * 8);
        }
        #pragma unroll
        for (int nf = 0; nf < 4; nf++) {
            int row = wn * 64 + nf * 16 + l15;
            int ch = l4 ^ ((row >> 1) & 3);
            bv[nf] = *(const short8*)(b0 + row * 32 + ch * 8);
        }
        __builtin_amdgcn_s_setprio(1);
        #pragma unroll
        for (int mf = 0; mf < 4; mf++)
            #pragma unroll
            for (int nf = 0; nf < 4; nf++)
                acc[mf][nf] = __builtin_amdgcn_mfma_f32_16x16x32_bf16(
                    af[mf], bv[nf], acc[mf][nf], 0, 0, 0);
        __builtin_amdgcn_s_setprio(0);

        const int rem = nt - 1 - t;        // tiles after this one
        if (rem == 0) break;               // last tile: no gate needed
        // gate: tile t+1 must be landed in ALL waves before anyone reads it.
        // per-wave outstanding after wait = 4 * (#tiles beyond t+1 in flight)
        if (rem >= 3)      asm volatile("s_waitcnt vmcnt(8)" ::: "memory");
        else if (rem == 2) asm volatile("s_waitcnt vmcnt(4)" ::: "memory");
        else               asm volatile("s_waitcnt vmcnt(0)" ::: "memory");
        __builtin_amdgcn_s_barrier();
        __builtin_amdgcn_sched_barrier(0);
    }

    #pragma unroll
    for (int nf = 0; nf < 4; nf++) {
        int col = col0 + wn * 64 + nf * 16 + l15;
        float sc = HAS_V ? (1.0f + v[col]) : 1.0f;
        #pragma unroll
        for (int mf = 0; mf < 4; mf++) {
            int row = row0 + wm * 64 + mf * 16 + l4 * 4;
            #pragma unroll
            for (int r2 = 0; r2 < 4; r2++)
                C[(size_t)(row + r2) * N + col] = acc[mf][nf][r2] * sc;
        }
    }
}

extern "C" void kernel_launch(void* const* d_in, const int* in_sizes, int n_in,
                              void* d_out, int out_size, void* d_ws, size_t ws_size,
                              hipStream_t stream) {
    const float* x   = (const float*)d_in[0];
    const float* W   = (const float*)d_in[1];
    const float* U   = (const float*)d_in[2];
    const float* V   = (const float*)d_in[3];
    const float* lam = (const float*)d_in[4];
    const float* v   = (const float*)d_in[5];
    const float* W1  = (const float*)d_in[6];
    const float* W2  = (const float*)d_in[7];
    float* out = (float*)d_out;

    char* ws = (char*)d_ws;
    u16*   Aaug = (u16*)ws;                               // 4096 x 2560 bf16 (x | m)
    u16*   BigB = (u16*)(ws + 20971520);                  // 2048 x 2560 bf16 (W | U)
    u16*   UVT  = (u16*)(ws + 31457280);                  // 1024 x 2048 bf16 (U^T ; V)
    float* rt   = (float*)(ws + 35651584);                // 4096 x 1024 f32 (r | t)

    cvt_copy2d<<<2048, 256, 0, stream>>>(x, Aaug, 4096, 512, 2048, 2560);
    cvt_copy2d<<<2048, 256, 0, stream>>>(W, BigB, 2048, 512, 2048, 2560);
    cvt_copy2d<<<1024, 256, 0, stream>>>(U, BigB + 2048, 2048, 128, 512, 2560);
    cvt_copy2d<<<2048, 256, 0, stream>>>(V, UVT + (size_t)512 * 2048, 512, 512, 2048, 2048);
    transpose_cvt<<<dim3(16, 64), dim3(32, 8), 0, stream>>>(U, UVT, 512, 2048);

    // GEMM1: rt(4096x1024) = xb @ [U^T;V]^T, K=2048. grid 8x32 = 256 blocks.
    gemm_r4<false><<<256, 256, 0, stream>>>(Aaug, UVT, rt, nullptr,
                                            1024, 2048, 2560, 2048, 8);

    router_kernel<<<4096, 256, 0, stream>>>(rt, W1, W2, lam, Aaug);

    // GEMM2: out(4096x2048) = [xb|m] @ [W|U]^T, K=2560. grid 16x32 = 512 blocks.
    gemm_r4<true><<<512, 256, 0, stream>>>(Aaug, BigB, out, v,
                                           2048, 2560, 2560, 2560, 16);
}

// Round 4
// 106.394 us; speedup vs baseline: 1.1153x; 1.1153x over previous
//
#include <hip/hip_runtime.h>
#include <hip/hip_bf16.h>
#include <cstdint>

#define B_TOK 4096
#define DDIM  2048
#define KR    512
#define NE    8

using f32x4  = __attribute__((ext_vector_type(4))) float;
using short8 = __attribute__((ext_vector_type(8))) short;
using u16 = unsigned short;

__device__ inline u16 f2bf(float f) {
    union { float f; uint32_t u; } x; x.f = f;
    uint32_t u = x.u;
    return (u16)((u + 0x7fffu + ((u >> 16) & 1u)) >> 16);  // RNE
}
__device__ inline float bf2f(u16 h) {
    union { uint32_t u; float f; } x; x.u = ((uint32_t)h) << 16;
    return x.f;
}

__device__ inline void gload_lds16(const u16* g, u16* l) {
    __builtin_amdgcn_global_load_lds(
        (const __attribute__((address_space(1))) void*)g,
        (__attribute__((address_space(3))) void*)l, 16, 0, 0);
}

// ---------------- conversion: f32 2D block -> bf16 2D block ----------------
__global__ void cvt_copy2d(const float* __restrict__ src, u16* __restrict__ dst,
                           int rows, int cols4, int src_ld, int dst_ld) {
    int total = rows * cols4;
    for (int i = blockIdx.x * blockDim.x + threadIdx.x; i < total;
         i += gridDim.x * blockDim.x) {
        int r = i / cols4, c = i - r * cols4;
        float4 val = *((const float4*)(src + (size_t)r * src_ld) + c);
        ushort4 o;
        o.x = f2bf(val.x); o.y = f2bf(val.y); o.z = f2bf(val.z); o.w = f2bf(val.w);
        *((ushort4*)(dst + (size_t)r * dst_ld) + c) = o;
    }
}

// ---------------- u1 = U @ W1 (D x 1), one wave per output row ----------------
__global__ __launch_bounds__(64)
void uw1_kernel(const float* __restrict__ U, const float* __restrict__ W1,
                float* __restrict__ u1) {
    int d = blockIdx.x, lane = threadIdx.x;
    const float* row = U + (size_t)d * KR;
    float s = 0.f;
    #pragma unroll
    for (int k = 0; k < KR; k += 64) s += row[k + lane] * W1[k + lane];
    #pragma unroll
    for (int o = 32; o > 0; o >>= 1) s += __shfl_down(s, o);
    if (lane == 0) u1[d] = s;
}

// ------- router: s = x.u1 ; g = softmax(s*W2) ; m = (g.lam) * t -> Aaug -------
__global__ __launch_bounds__(256)
void router2(const u16* __restrict__ Ax, const float* __restrict__ u1,
             const float* __restrict__ W2, const float* __restrict__ lam,
             const float* __restrict__ tmat, u16* __restrict__ Am) {
    int b = blockIdx.x, tid = threadIdx.x;
    const u16* xr = Ax + (size_t)b * 2560;

    short8 xv = *(const short8*)(xr + tid * 8);
    float4 ua = *((const float4*)(u1 + tid * 8));
    float4 ub = *((const float4*)(u1 + tid * 8) + 1);
    float p = bf2f((u16)xv[0]) * ua.x + bf2f((u16)xv[1]) * ua.y +
              bf2f((u16)xv[2]) * ua.z + bf2f((u16)xv[3]) * ua.w +
              bf2f((u16)xv[4]) * ub.x + bf2f((u16)xv[5]) * ub.y +
              bf2f((u16)xv[6]) * ub.z + bf2f((u16)xv[7]) * ub.w;
    #pragma unroll
    for (int o = 32; o > 0; o >>= 1) p += __shfl_down(p, o);
    __shared__ float sp4[4];
    __shared__ float sbc;
    if ((tid & 63) == 0) sp4[tid >> 6] = p;
    __syncthreads();
    if (tid == 0) sbc = sp4[0] + sp4[1] + sp4[2] + sp4[3];
    __syncthreads();
    float s = sbc;

    float g[NE]; float mx = -1e30f;
    #pragma unroll
    for (int e = 0; e < NE; e++) { g[e] = s * W2[e]; mx = fmaxf(mx, g[e]); }
    float den = 0.f;
    #pragma unroll
    for (int e = 0; e < NE; e++) { g[e] = expf(g[e] - mx); den += g[e]; }
    float inv = 1.0f / den;

    for (int kk = tid; kk < KR; kk += 256) {
        float mu = 0.f;
        #pragma unroll
        for (int e = 0; e < NE; e++) mu += g[e] * lam[e * KR + kk];
        Am[(size_t)b * 2560 + 2048 + kk] =
            f2bf(mu * inv * tmat[(size_t)b * KR + kk]);
    }
}

// -------- round-2 proven GEMM (2-buffer, BK=64, drain at barrier) for GEMM1 ----
template<int BM, int BN, int WGM, int WGN, bool HAS_V>
__global__ __launch_bounds__(256, 2)
void gemm_db(const u16* __restrict__ A, const u16* __restrict__ Bm,
             float* __restrict__ C, const float* __restrict__ v,
             int N, int Kc, int lda, int ldb, int nbx) {
    constexpr int MF = BM / (WGM * 16);
    constexpr int NF = BN / (WGN * 16);
    constexpr int ISSA = BM / 32;
    constexpr int ISSB = BN / 32;
    __shared__ u16 sA[2 * BM * 64];
    __shared__ u16 sB[2 * BN * 64];

    const int tid = threadIdx.x;
    const int wid = tid >> 6, lane = tid & 63;
    const int l15 = lane & 15, l4 = lane >> 4;
    const int wm = wid / WGN, wn = wid % WGN;

    const int nwg = gridDim.x;
    const int id = (blockIdx.x & 7) * (nwg >> 3) + (blockIdx.x >> 3);
    const int row0 = (id / nbx) * BM;
    const int col0 = (id % nbx) * BN;

    const int srow = tid >> 3;
    const int scol = ((tid & 7) ^ (srow & 7)) << 3;
    const u16* gA = A + (size_t)(row0 + srow) * lda + scol;
    const u16* gB = Bm + (size_t)(col0 + srow) * ldb + scol;

    f32x4 acc[MF][NF] = {};
    const int nt = Kc >> 6;

    #pragma unroll
    for (int i = 0; i < ISSA; i++)
        gload_lds16(gA + (size_t)i * 32 * lda, sA + i * 2048 + wid * 512);
    #pragma unroll
    for (int i = 0; i < ISSB; i++)
        gload_lds16(gB + (size_t)i * 32 * ldb, sB + i * 2048 + wid * 512);
    __syncthreads();

    for (int t = 0; t < nt; ++t) {
        const int cur = t & 1;
        if (t + 1 < nt) {
            const int nxt = cur ^ 1;
            const u16* gAk = gA + (size_t)(t + 1) * 64;
            const u16* gBk = gB + (size_t)(t + 1) * 64;
            #pragma unroll
            for (int i = 0; i < ISSA; i++)
                gload_lds16(gAk + (size_t)i * 32 * lda,
                            sA + nxt * BM * 64 + i * 2048 + wid * 512);
            #pragma unroll
            for (int i = 0; i < ISSB; i++)
                gload_lds16(gBk + (size_t)i * 32 * ldb,
                            sB + nxt * BN * 64 + i * 2048 + wid * 512);
        }
        const u16* a0 = sA + cur * BM * 64;
        const u16* b0 = sB + cur * BN * 64;
        #pragma unroll
        for (int kc = 0; kc < 8; kc += 4) {
            short8 af[MF], bv[NF];
            #pragma unroll
            for (int mf = 0; mf < MF; mf++) {
                int row = wm * MF * 16 + mf * 16 + l15;
                int ch = (kc + l4) ^ (row & 7);
                af[mf] = *(const short8*)(a0 + row * 64 + ch * 8);
            }
            #pragma unroll
            for (int nf = 0; nf < NF; nf++) {
                int row = wn * NF * 16 + nf * 16 + l15;
                int ch = (kc + l4) ^ (row & 7);
                bv[nf] = *(const short8*)(b0 + row * 64 + ch * 8);
            }
            #pragma unroll
            for (int mf = 0; mf < MF; mf++)
                #pragma unroll
                for (int nf = 0; nf < NF; nf++)
                    acc[mf][nf] = __builtin_amdgcn_mfma_f32_16x16x32_bf16(
                        af[mf], bv[nf], acc[mf][nf], 0, 0, 0);
        }
        __syncthreads();
    }

    #pragma unroll
    for (int nf = 0; nf < NF; nf++) {
        int col = col0 + wn * NF * 16 + nf * 16 + l15;
        float sc = HAS_V ? (1.0f + v[col]) : 1.0f;
        #pragma unroll
        for (int mf = 0; mf < MF; mf++) {
            int row = row0 + wm * MF * 16 + mf * 16 + l4 * 4;
            #pragma unroll
            for (int r2 = 0; r2 < 4; r2++)
                C[(size_t)(row + r2) * N + col] = acc[mf][nf][r2] * sc;
        }
    }
}

// ---- GEMM2: 256x128 tile, BK=64, 3-slot LDS ring (144KB), prefetch depth 2,
// ---- counted vmcnt(6) gates (T4), raw s_barrier, setprio (T5), T2 swizzle.
template<int BM, int BN, int WGM, int WGN, bool HAS_V>
__global__ __launch_bounds__(WGM * WGN * 64, 1)
void gemm_ring(const u16* __restrict__ A, const u16* __restrict__ Bm,
               float* __restrict__ C, const float* __restrict__ v,
               int N, int Kc, int lda, int ldb, int nbx) {
    constexpr int NT = WGM * WGN * 64;
    constexpr int MF = BM / (WGM * 16);
    constexpr int NF = BN / (WGN * 16);
    constexpr int SLOT = (BM + BN) * 64;        // u16 per ring slot
    constexpr int ROWS = NT / 8;                // rows staged per issue
    constexpr int ISSA = BM / ROWS;
    constexpr int ISSB = BN / ROWS;
    static_assert(ISSA + ISSB == 6, "vmcnt literals assume 6 loads/tile");
    __shared__ u16 lds[3 * SLOT];               // 144 KB for 256x128

    const int tid = threadIdx.x;
    const int wid = tid >> 6, lane = tid & 63;
    const int l15 = lane & 15, l4 = lane >> 4;
    const int wm = wid / WGN, wn = wid % WGN;

    const int nwg = gridDim.x;
    const int id = (blockIdx.x & 7) * (nwg >> 3) + (blockIdx.x >> 3);
    const int row0 = (id / nbx) * BM;
    const int col0 = (id % nbx) * BN;

    const int srow = tid >> 3;
    const int scol = ((tid & 7) ^ (srow & 7)) << 3;
    const u16* gA = A + (size_t)(row0 + srow) * lda + scol;
    const u16* gB = Bm + (size_t)(col0 + srow) * ldb + scol;

    f32x4 acc[MF][NF] = {};
    const int nt = Kc >> 6;

    // prologue: stage tiles 0,1 into slots 0,1 (nt >= 3 here)
    #pragma unroll
    for (int p = 0; p < 2; p++) {
        const u16* gAt = gA + p * 64;
        const u16* gBt = gB + p * 64;
        u16* sl = lds + p * SLOT;
        #pragma unroll
        for (int i = 0; i < ISSA; i++)
            gload_lds16(gAt + (size_t)i * ROWS * lda,
                        sl + i * ROWS * 64 + wid * 512);
        #pragma unroll
        for (int i = 0; i < ISSB; i++)
            gload_lds16(gBt + (size_t)i * ROWS * ldb,
                        sl + BM * 64 + i * ROWS * 64 + wid * 512);
    }
    asm volatile("s_waitcnt vmcnt(6)" ::: "memory");   // tile 0 landed
    __builtin_amdgcn_s_barrier();
    asm volatile("" ::: "memory");

    int sc = 0, sp = 2;   // slot of tile t / tile t+2
    for (int t = 0; t < nt; ++t) {
        if (t + 2 < nt) {
            const u16* gAt = gA + (size_t)(t + 2) * 64;
            const u16* gBt = gB + (size_t)(t + 2) * 64;
            u16* sl = lds + sp * SLOT;
            #pragma unroll
            for (int i = 0; i < ISSA; i++)
                gload_lds16(gAt + (size_t)i * ROWS * lda,
                            sl + i * ROWS * 64 + wid * 512);
            #pragma unroll
            for (int i = 0; i < ISSB; i++)
                gload_lds16(gBt + (size_t)i * ROWS * ldb,
                            sl + BM * 64 + i * ROWS * 64 + wid * 512);
        }
        const u16* a0 = lds + sc * SLOT;
        const u16* b0 = a0 + BM * 64;
        __builtin_amdgcn_s_setprio(1);
        #pragma unroll
        for (int kc = 0; kc < 8; kc += 4) {
            short8 af[MF], bv[NF];
            #pragma unroll
            for (int mf = 0; mf < MF; mf++) {
                int row = wm * MF * 16 + mf * 16 + l15;
                int ch = (kc + l4) ^ (row & 7);
                af[mf] = *(const short8*)(a0 + row * 64 + ch * 8);
            }
            #pragma unroll
            for (int nf = 0; nf < NF; nf++) {
                int row = wn * NF * 16 + nf * 16 + l15;
                int ch = (kc + l4) ^ (row & 7);
                bv[nf] = *(const short8*)(b0 + row * 64 + ch * 8);
            }
            #pragma unroll
            for (int mf = 0; mf < MF; mf++)
                #pragma unroll
                for (int nf = 0; nf < NF; nf++)
                    acc[mf][nf] = __builtin_amdgcn_mfma_f32_16x16x32_bf16(
                        af[mf], bv[nf], acc[mf][nf], 0, 0, 0);
        }
        __builtin_amdgcn_s_setprio(0);

        const int rem = nt - 1 - t;
        if (rem == 0) break;
        // gate: tile t+1 must be resident; keep tile t+2's 6 loads in flight
        if (rem >= 2) asm volatile("s_waitcnt vmcnt(6)" ::: "memory");
        else          asm volatile("s_waitcnt vmcnt(0)" ::: "memory");
        __builtin_amdgcn_s_barrier();
        asm volatile("" ::: "memory");
        sc = (sc == 2) ? 0 : sc + 1;
        sp = (sp == 2) ? 0 : sp + 1;
    }

    #pragma unroll
    for (int nf = 0; nf < NF; nf++) {
        int col = col0 + wn * NF * 16 + nf * 16 + l15;
        float sc2 = HAS_V ? (1.0f + v[col]) : 1.0f;
        #pragma unroll
        for (int mf = 0; mf < MF; mf++) {
            int row = row0 + wm * MF * 16 + mf * 16 + l4 * 4;
            #pragma unroll
            for (int r2 = 0; r2 < 4; r2++)
                C[(size_t)(row + r2) * N + col] = acc[mf][nf][r2] * sc2;
        }
    }
}

extern "C" void kernel_launch(void* const* d_in, const int* in_sizes, int n_in,
                              void* d_out, int out_size, void* d_ws, size_t ws_size,
                              hipStream_t stream) {
    const float* x   = (const float*)d_in[0];
    const float* W   = (const float*)d_in[1];
    const float* U   = (const float*)d_in[2];
    const float* V   = (const float*)d_in[3];
    const float* lam = (const float*)d_in[4];
    const float* v   = (const float*)d_in[5];
    const float* W1  = (const float*)d_in[6];
    const float* W2  = (const float*)d_in[7];
    float* out = (float*)d_out;

    char* ws = (char*)d_ws;
    u16*   Aaug = (u16*)ws;                        // 4096 x 2560 bf16 (x | m)
    u16*   BigB = (u16*)(ws + 20971520);           // 2048 x 2560 bf16 (W | U)
    u16*   Vb   = (u16*)(ws + 31457280);           // 512 x 2048 bf16 (V)
    float* tmat = (float*)(ws + 33554432);         // 4096 x 512 f32 (t = x V^T)
    float* u1   = (float*)(ws + 41943040);         // 2048 f32 (U @ W1)

    cvt_copy2d<<<2048, 256, 0, stream>>>(x, Aaug, 4096, 512, 2048, 2560);
    cvt_copy2d<<<2048, 256, 0, stream>>>(W, BigB, 2048, 512, 2048, 2560);
    cvt_copy2d<<<1024, 256, 0, stream>>>(U, BigB + 2048, 2048, 128, 512, 2560);
    cvt_copy2d<<<1024, 256, 0, stream>>>(V, Vb, 512, 512, 2048, 2048);
    uw1_kernel<<<2048, 64, 0, stream>>>(U, W1, u1);

    // GEMM1: t(4096x512) = xb @ V^T, K=2048. grid 32x8 = 256 blocks.
    gemm_db<128, 64, 4, 1, false><<<256, 256, 0, stream>>>(
        Aaug, Vb, tmat, nullptr, 512, 2048, 2560, 2048, 8);

    router2<<<4096, 256, 0, stream>>>(Aaug, u1, W2, lam, tmat, Aaug);

    // GEMM2: out(4096x2048) = [xb|m] @ [W|U]^T, K=2560. grid 16x16 = 256 blocks.
    gemm_ring<256, 128, 4, 2, true><<<256, 512, 0, stream>>>(
        Aaug, BigB, out, v, 2048, 2560, 2560, 2560, 16);
}

// Round 5
// 101.858 us; speedup vs baseline: 1.1650x; 1.0445x over previous
//
#include <hip/hip_runtime.h>
#include <hip/hip_bf16.h>
#include <cstdint>

#define B_TOK 4096
#define DDIM  2048
#define KR    512
#define NE    8

using f32x4  = __attribute__((ext_vector_type(4))) float;
using short8 = __attribute__((ext_vector_type(8))) short;
using u16 = unsigned short;

__device__ inline u16 f2bf(float f) {
    union { float f; uint32_t u; } x; x.f = f;
    uint32_t u = x.u;
    return (u16)((u + 0x7fffu + ((u >> 16) & 1u)) >> 16);  // RNE
}
__device__ inline float bf2f(u16 h) {
    union { uint32_t u; float f; } x; x.u = ((uint32_t)h) << 16;
    return x.f;
}

__device__ inline void gload_lds16(const u16* g, u16* l) {
    __builtin_amdgcn_global_load_lds(
        (const __attribute__((address_space(1))) void*)g,
        (__attribute__((address_space(3))) void*)l, 16, 0, 0);
}

// ---------------- fused prep: 4 f32->bf16 copies + u1 = U@W1 ----------------
template<int COLS4, int SRC_LD, int DST_LD>
__device__ inline void cvt_region(const float* __restrict__ src,
                                  u16* __restrict__ dst, int i) {
    int r = i / COLS4, c = i - r * COLS4;
    float4 val = *((const float4*)(src + (size_t)r * SRC_LD) + c);
    ushort4 o;
    o.x = f2bf(val.x); o.y = f2bf(val.y); o.z = f2bf(val.z); o.w = f2bf(val.w);
    *(ushort4*)(dst + (size_t)r * DST_LD + c * 4) = o;
}

__global__ __launch_bounds__(256)
void prep_all(const float* __restrict__ x, const float* __restrict__ W,
              const float* __restrict__ U, const float* __restrict__ V,
              const float* __restrict__ W1,
              u16* __restrict__ Aaug, u16* __restrict__ BigB,
              u16* __restrict__ Vb, float* __restrict__ u1) {
    constexpr int NB_COPY = 1792;
    constexpr int N_X = 4096 * 512;          // 2097152
    constexpr int N_W = 2048 * 512;          // 1048576
    constexpr int N_U = 2048 * 128;          // 262144
    constexpr int N_V = 512 * 512;           // 262144
    constexpr int N_TOT = N_X + N_W + N_U + N_V;
    int b = blockIdx.x;
    if (b < NB_COPY) {
        for (int i = b * 256 + threadIdx.x; i < N_TOT; i += NB_COPY * 256) {
            if (i < N_X)                cvt_region<512, 2048, 2560>(x, Aaug, i);
            else if (i < N_X + N_W)     cvt_region<512, 2048, 2560>(W, BigB, i - N_X);
            else if (i < N_X + N_W + N_U)
                cvt_region<128, 512, 2560>(U, BigB + 2048, i - N_X - N_W);
            else                        cvt_region<512, 2048, 2048>(V, Vb, i - N_X - N_W - N_U);
        }
    } else {
        int wrow = (b - NB_COPY) * 4 + (threadIdx.x >> 6);
        int lane = threadIdx.x & 63;
        const float* row = U + (size_t)wrow * KR;
        float s = 0.f;
        #pragma unroll
        for (int k = 0; k < KR; k += 64) s += row[k + lane] * W1[k + lane];
        #pragma unroll
        for (int o = 32; o > 0; o >>= 1) s += __shfl_down(s, o);
        if (lane == 0) u1[wrow] = s;
    }
}

// ------- router: s = x.u1 ; g = softmax(s*W2) ; m = (g.lam) * t -> Aaug -------
__global__ __launch_bounds__(256)
void router2(const u16* __restrict__ Ax, const float* __restrict__ u1,
             const float* __restrict__ W2, const float* __restrict__ lam,
             const float* __restrict__ tmat, u16* __restrict__ Am) {
    int b = blockIdx.x, tid = threadIdx.x;
    const u16* xr = Ax + (size_t)b * 2560;

    short8 xv = *(const short8*)(xr + tid * 8);
    float4 ua = *((const float4*)(u1 + tid * 8));
    float4 ub = *((const float4*)(u1 + tid * 8) + 1);
    float p = bf2f((u16)xv[0]) * ua.x + bf2f((u16)xv[1]) * ua.y +
              bf2f((u16)xv[2]) * ua.z + bf2f((u16)xv[3]) * ua.w +
              bf2f((u16)xv[4]) * ub.x + bf2f((u16)xv[5]) * ub.y +
              bf2f((u16)xv[6]) * ub.z + bf2f((u16)xv[7]) * ub.w;
    #pragma unroll
    for (int o = 32; o > 0; o >>= 1) p += __shfl_down(p, o);
    __shared__ float sp4[4];
    __shared__ float sbc;
    if ((tid & 63) == 0) sp4[tid >> 6] = p;
    __syncthreads();
    if (tid == 0) sbc = sp4[0] + sp4[1] + sp4[2] + sp4[3];
    __syncthreads();
    float s = sbc;

    float g[NE]; float mx = -1e30f;
    #pragma unroll
    for (int e = 0; e < NE; e++) { g[e] = s * W2[e]; mx = fmaxf(mx, g[e]); }
    float den = 0.f;
    #pragma unroll
    for (int e = 0; e < NE; e++) { g[e] = expf(g[e] - mx); den += g[e]; }
    float inv = 1.0f / den;

    for (int kk = tid; kk < KR; kk += 256) {
        float mu = 0.f;
        #pragma unroll
        for (int e = 0; e < NE; e++) mu += g[e] * lam[e * KR + kk];
        Am[(size_t)b * 2560 + 2048 + kk] =
            f2bf(mu * inv * tmat[(size_t)b * KR + kk]);
    }
}

// -------- GEMM1 kernel (round-2 proven structure, 2-buffer BK=64) ----------
template<int BM, int BN, int WGM, int WGN, bool HAS_V>
__global__ __launch_bounds__(256, 2)
void gemm_db(const u16* __restrict__ A, const u16* __restrict__ Bm,
             float* __restrict__ C, const float* __restrict__ v,
             int N, int Kc, int lda, int ldb, int nbx) {
    constexpr int MF = BM / (WGM * 16);
    constexpr int NF = BN / (WGN * 16);
    constexpr int ISSA = BM / 32;
    constexpr int ISSB = BN / 32;
    __shared__ u16 sA[2 * BM * 64];
    __shared__ u16 sB[2 * BN * 64];

    const int tid = threadIdx.x;
    const int wid = tid >> 6, lane = tid & 63;
    const int l15 = lane & 15, l4 = lane >> 4;
    const int wm = wid / WGN, wn = wid % WGN;

    const int nwg = gridDim.x;
    const int id = (blockIdx.x & 7) * (nwg >> 3) + (blockIdx.x >> 3);
    const int row0 = (id / nbx) * BM;
    const int col0 = (id % nbx) * BN;

    const int srow = tid >> 3;
    const int scol = ((tid & 7) ^ (srow & 7)) << 3;
    const u16* gA = A + (size_t)(row0 + srow) * lda + scol;
    const u16* gB = Bm + (size_t)(col0 + srow) * ldb + scol;

    f32x4 acc[MF][NF] = {};
    const int nt = Kc >> 6;

    #pragma unroll
    for (int i = 0; i < ISSA; i++)
        gload_lds16(gA + (size_t)i * 32 * lda, sA + i * 2048 + wid * 512);
    #pragma unroll
    for (int i = 0; i < ISSB; i++)
        gload_lds16(gB + (size_t)i * 32 * ldb, sB + i * 2048 + wid * 512);
    __syncthreads();

    for (int t = 0; t < nt; ++t) {
        const int cur = t & 1;
        if (t + 1 < nt) {
            const int nxt = cur ^ 1;
            const u16* gAk = gA + (size_t)(t + 1) * 64;
            const u16* gBk = gB + (size_t)(t + 1) * 64;
            #pragma unroll
            for (int i = 0; i < ISSA; i++)
                gload_lds16(gAk + (size_t)i * 32 * lda,
                            sA + nxt * BM * 64 + i * 2048 + wid * 512);
            #pragma unroll
            for (int i = 0; i < ISSB; i++)
                gload_lds16(gBk + (size_t)i * 32 * ldb,
                            sB + nxt * BN * 64 + i * 2048 + wid * 512);
        }
        const u16* a0 = sA + cur * BM * 64;
        const u16* b0 = sB + cur * BN * 64;
        #pragma unroll
        for (int kc = 0; kc < 8; kc += 4) {
            short8 af[MF], bv[NF];
            #pragma unroll
            for (int mf = 0; mf < MF; mf++) {
                int row = wm * MF * 16 + mf * 16 + l15;
                int ch = (kc + l4) ^ (row & 7);
                af[mf] = *(const short8*)(a0 + row * 64 + ch * 8);
            }
            #pragma unroll
            for (int nf = 0; nf < NF; nf++) {
                int row = wn * NF * 16 + nf * 16 + l15;
                int ch = (kc + l4) ^ (row & 7);
                bv[nf] = *(const short8*)(b0 + row * 64 + ch * 8);
            }
            #pragma unroll
            for (int mf = 0; mf < MF; mf++)
                #pragma unroll
                for (int nf = 0; nf < NF; nf++)
                    acc[mf][nf] = __builtin_amdgcn_mfma_f32_16x16x32_bf16(
                        af[mf], bv[nf], acc[mf][nf], 0, 0, 0);
        }
        __syncthreads();
    }

    #pragma unroll
    for (int nf = 0; nf < NF; nf++) {
        int col = col0 + wn * NF * 16 + nf * 16 + l15;
        float sc = HAS_V ? (1.0f + v[col]) : 1.0f;
        #pragma unroll
        for (int mf = 0; mf < MF; mf++) {
            int row = row0 + wm * MF * 16 + mf * 16 + l4 * 4;
            #pragma unroll
            for (int r2 = 0; r2 < 4; r2++)
                C[(size_t)(row + r2) * N + col] = acc[mf][nf][r2] * sc;
        }
    }
}

// ---- GEMM2: 256x128, BK=64, 3-slot ring (same ledger as round-4: stage t+2,
// ---- gate vmcnt(6) per tile), NOW with 2 lockstep phases per K-tile:
// ---- {8 ds_read ; 3 gload ; barrier ; lgkmcnt(0) ; setprio(1) ; 16 MFMA ;
// ----  setprio(0) ; [gate] ; barrier}  (m201-style fine interleave, T3+T4+T5)
template<int BM, int BN, int WGM, int WGN, bool HAS_V>
__global__ __launch_bounds__(WGM * WGN * 64, 1)
void gemm_ph(const u16* __restrict__ A, const u16* __restrict__ Bm,
             float* __restrict__ C, const float* __restrict__ v,
             int N, int Kc, int lda, int ldb, int nbx) {
    constexpr int NT = WGM * WGN * 64;          // 512 threads
    constexpr int MF = BM / (WGM * 16);         // 4
    constexpr int NF = BN / (WGN * 16);         // 4
    constexpr int SLOT = (BM + BN) * 64;        // u16 per ring slot (48KB)
    constexpr int ROWS = NT / 8;                // 64 rows per issue
    constexpr int ISSA = BM / ROWS;             // 4
    constexpr int ISSB = BN / ROWS;             // 2
    static_assert(ISSA + ISSB == 6, "vmcnt literals assume 6 loads/tile");
    __shared__ u16 lds[3 * SLOT];               // 144 KB

    const int tid = threadIdx.x;
    const int wid = tid >> 6, lane = tid & 63;
    const int l15 = lane & 15, l4 = lane >> 4;
    const int wm = wid / WGN, wn = wid % WGN;

    const int nwg = gridDim.x;
    const int id = (blockIdx.x & 7) * (nwg >> 3) + (blockIdx.x >> 3);
    const int row0 = (id / nbx) * BM;
    const int col0 = (id % nbx) * BN;

    const int srow = tid >> 3;
    const int scol = ((tid & 7) ^ (srow & 7)) << 3;
    const u16* gA = A + (size_t)(row0 + srow) * lda + scol;
    const u16* gB = Bm + (size_t)(col0 + srow) * ldb + scol;

    f32x4 acc[MF][NF] = {};
    const int nt = Kc >> 6;

    // prologue: stage tiles 0,1 into slots 0,1
    #pragma unroll
    for (int p = 0; p < 2; p++) {
        const u16* gAt = gA + p * 64;
        const u16* gBt = gB + p * 64;
        u16* sl = lds + p * SLOT;
        #pragma unroll
        for (int i = 0; i < ISSA; i++)
            gload_lds16(gAt + (size_t)i * ROWS * lda,
                        sl + i * ROWS * 64 + wid * 512);
        #pragma unroll
        for (int i = 0; i < ISSB; i++)
            gload_lds16(gBt + (size_t)i * ROWS * ldb,
                        sl + BM * 64 + i * ROWS * 64 + wid * 512);
    }
    asm volatile("s_waitcnt vmcnt(6)" ::: "memory");   // tile 0 resident
    __builtin_amdgcn_s_barrier();

    int sc = 0, sp = 2;   // slot of tile t / staging slot of tile t+2
    for (int t = 0; t < nt; ++t) {
        const u16* a0 = lds + sc * SLOT;
        const u16* b0 = a0 + BM * 64;
        const u16* gAt = gA + (size_t)(t + 2) * 64;
        const u16* gBt = gB + (size_t)(t + 2) * 64;
        u16* sl = lds + sp * SLOT;
        const bool pf = (t + 2 < nt);

        // ===== phase 0 (k-chunk base 0) =====
        short8 af[MF], bv[NF];
        #pragma unroll
        for (int mf = 0; mf < MF; mf++) {
            int row = wm * MF * 16 + mf * 16 + l15;
            int ch = l4 ^ (row & 7);
            af[mf] = *(const short8*)(a0 + row * 64 + ch * 8);
        }
        #pragma unroll
        for (int nf = 0; nf < NF; nf++) {
            int row = wn * NF * 16 + nf * 16 + l15;
            int ch = l4 ^ (row & 7);
            bv[nf] = *(const short8*)(b0 + row * 64 + ch * 8);
        }
        if (pf) {   // stage A-issues 0..2 of tile t+2
            gload_lds16(gAt,                         sl + wid * 512);
            gload_lds16(gAt + (size_t)ROWS * lda,    sl + ROWS * 64 + wid * 512);
            gload_lds16(gAt + (size_t)2 * ROWS * lda, sl + 2 * ROWS * 64 + wid * 512);
        }
        __builtin_amdgcn_s_barrier();
        asm volatile("s_waitcnt lgkmcnt(0)" ::: "memory");
        __builtin_amdgcn_s_setprio(1);
        #pragma unroll
        for (int mf = 0; mf < MF; mf++)
            #pragma unroll
            for (int nf = 0; nf < NF; nf++)
                acc[mf][nf] = __builtin_amdgcn_mfma_f32_16x16x32_bf16(
                    af[mf], bv[nf], acc[mf][nf], 0, 0, 0);
        __builtin_amdgcn_s_setprio(0);
        __builtin_amdgcn_s_barrier();

        // ===== phase 1 (k-chunk base 4) =====
        #pragma unroll
        for (int mf = 0; mf < MF; mf++) {
            int row = wm * MF * 16 + mf * 16 + l15;
            int ch = (4 + l4) ^ (row & 7);
            af[mf] = *(const short8*)(a0 + row * 64 + ch * 8);
        }
        #pragma unroll
        for (int nf = 0; nf < NF; nf++) {
            int row = wn * NF * 16 + nf * 16 + l15;
            int ch = (4 + l4) ^ (row & 7);
            bv[nf] = *(const short8*)(b0 + row * 64 + ch * 8);
        }
        if (pf) {   // stage A-issue 3 + B-issues 0,1 of tile t+2
            gload_lds16(gAt + (size_t)3 * ROWS * lda, sl + 3 * ROWS * 64 + wid * 512);
            gload_lds16(gBt,                          sl + BM * 64 + wid * 512);
            gload_lds16(gBt + (size_t)ROWS * ldb,     sl + BM * 64 + ROWS * 64 + wid * 512);
        }
        __builtin_amdgcn_s_barrier();
        asm volatile("s_waitcnt lgkmcnt(0)" ::: "memory");
        __builtin_amdgcn_s_setprio(1);
        #pragma unroll
        for (int mf = 0; mf < MF; mf++)
            #pragma unroll
            for (int nf = 0; nf < NF; nf++)
                acc[mf][nf] = __builtin_amdgcn_mfma_f32_16x16x32_bf16(
                    af[mf], bv[nf], acc[mf][nf], 0, 0, 0);
        __builtin_amdgcn_s_setprio(0);

        const int rem = nt - 1 - t;
        if (rem == 0) break;
        // gate: tile t+1 must be resident; only t+2's 6 loads may stay in flight
        if (rem >= 2) asm volatile("s_waitcnt vmcnt(6)" ::: "memory");
        else          asm volatile("s_waitcnt vmcnt(0)" ::: "memory");
        __builtin_amdgcn_s_barrier();
        sc = (sc == 2) ? 0 : sc + 1;
        sp = (sp == 2) ? 0 : sp + 1;
    }

    #pragma unroll
    for (int nf = 0; nf < NF; nf++) {
        int col = col0 + wn * NF * 16 + nf * 16 + l15;
        float sc2 = HAS_V ? (1.0f + v[col]) : 1.0f;
        #pragma unroll
        for (int mf = 0; mf < MF; mf++) {
            int row = row0 + wm * MF * 16 + mf * 16 + l4 * 4;
            #pragma unroll
            for (int r2 = 0; r2 < 4; r2++)
                C[(size_t)(row + r2) * N + col] = acc[mf][nf][r2] * sc2;
        }
    }
}

extern "C" void kernel_launch(void* const* d_in, const int* in_sizes, int n_in,
                              void* d_out, int out_size, void* d_ws, size_t ws_size,
                              hipStream_t stream) {
    const float* x   = (const float*)d_in[0];
    const float* W   = (const float*)d_in[1];
    const float* U   = (const float*)d_in[2];
    const float* V   = (const float*)d_in[3];
    const float* lam = (const float*)d_in[4];
    const float* v   = (const float*)d_in[5];
    const float* W1  = (const float*)d_in[6];
    const float* W2  = (const float*)d_in[7];
    float* out = (float*)d_out;

    char* ws = (char*)d_ws;
    u16*   Aaug = (u16*)ws;                        // 4096 x 2560 bf16 (x | m)
    u16*   BigB = (u16*)(ws + 20971520);           // 2048 x 2560 bf16 (W | U)
    u16*   Vb   = (u16*)(ws + 31457280);           // 512 x 2048 bf16 (V)
    float* tmat = (float*)(ws + 33554432);         // 4096 x 512 f32 (t = x V^T)
    float* u1   = (float*)(ws + 41943040);         // 2048 f32 (U @ W1)

    // fused prep: all f32->bf16 conversions + u1 = U@W1, one dispatch
    prep_all<<<2304, 256, 0, stream>>>(x, W, U, V, W1, Aaug, BigB, Vb, u1);

    // GEMM1: t(4096x512) = xb @ V^T, K=2048. grid 32x8 = 256 blocks.
    gemm_db<128, 64, 4, 1, false><<<256, 256, 0, stream>>>(
        Aaug, Vb, tmat, nullptr, 512, 2048, 2560, 2048, 8);

    router2<<<4096, 256, 0, stream>>>(Aaug, u1, W2, lam, tmat, Aaug);

    // GEMM2: out(4096x2048) = [xb|m] @ [W|U]^T, K=2560. grid 16x16 = 256 blocks.
    gemm_ph<256, 128, 4, 2, true><<<256, 512, 0, stream>>>(
        Aaug, BigB, out, v, 2048, 2560, 2560, 2560, 16);
}